// Round 4
// baseline (182.939 us; speedup 1.0000x reference)
//
#include <hip/hip_runtime.h>
#include <cstdint>

#define BB 2
#define NN 16384
#define MM 4096
#define CF 256
#define CT 128
#define CP 64

// ======================= kernel 1: 3-NN -> workspace =======================
// Round-4: BRANCHLESS scan. Rounds 2/3 measured the __any pruning gate at
// ~60-100% taken (back-computed from VALUBusy x dur / wave-steps) -> the gate
// was pure overhead. This version removes gate/tau/shfl machinery entirely:
// every pair runs the 12-instr exact update network straight-line.
//  - Q=2 queries per lane (S=16 sub-lanes/query): one ds_read_b128 feeds two
//    distance computations -> LDS-pipe instrs halve, loop overhead halves.
//  - inner loop unrolled x32 with compile-time LDS offsets (ds_read offset:)
//    -> zero per-step address arithmetic.
// Bit-exactness: identical dd formula (pre-doubled refs, numpy sum order,
// contract off), ascending-j per-lane scan, strict-< index network, value
// network via min/med3 (exact selection), lexicographic butterfly merge.
#define TPB1 512
#define NPB1 64
#define CHUNK 2048

__global__ __launch_bounds__(TPB1, 4) void knn_kernel(
    const float* __restrict__ coords,      // [B,N,3]
    const float* __restrict__ ref_coords,  // [B,M,3]
    int4* __restrict__ wsI,                // [B,N] {i0,i1,i2,-}
    float4* __restrict__ wsW)              // [B,N] {w0,w1,w2,-}
{
#pragma clang fp contract(off)
    __shared__ float4 refs[CHUNK];      // 32 KB (2x, 2y, 2z, rr)

    const int tid = threadIdx.x;
    const int b   = blockIdx.y;
    const int n0  = blockIdx.x * NPB1;

    const int pl = tid >> 4;            // query-group 0..31
    const int s  = tid & 15;            // sub-lane 0..15
    const int nA = n0 + pl * 2;         // this lane's two queries
    // nB = nA + 1 (contiguous -> coords load is 6 consecutive floats)

    const float* cp = coords + ((size_t)b * NN + nA) * 3;
    const float ax = cp[0], ay = cp[1], az = cp[2];
    const float bx = cp[3], by = cp[4], bz = cp[5];
    const float acc_ = (ax * ax + ay * ay) + az * az;   // numpy sum order
    const float bcc_ = (bx * bx + by * by) + bz * bz;

    float aD0 = INFINITY, aD1 = INFINITY, aD2 = INFINITY;
    float bD0 = INFINITY, bD1 = INFINITY, bD2 = INFINITY;
    int   aI0 = 0, aI1 = 0, aI2 = 0;
    int   bI0 = 0, bI1 = 0, bI2 = 0;

    const float* rc = ref_coords + (size_t)b * MM * 3;

    for (int ch = 0; ch < MM / CHUNK; ++ch) {
        __syncthreads();                 // refs[] reuse guard
        for (int e = tid; e < CHUNK; e += TPB1) {
            const int j = ch * CHUNK + e;
            const float x = rc[3 * j + 0];
            const float y = rc[3 * j + 1];
            const float z = rc[3 * j + 2];
            // rr from ORIGINAL coords (numpy order); xyz pre-doubled (exact:
            // fl(c*(2r)) = 2*fl(c*r), fl(2a+2b) = 2*fl(a+b) at these scales)
            refs[e] = make_float4(x + x, y + y, z + z, (x * x + y * y) + z * z);
        }
        __syncthreads();

        const float4* rp = &refs[s];
        const int jb0 = ch * CHUNK + s;
        for (int kb = 0; kb < CHUNK / 16 / 32; ++kb) {   // 4 blocks of 32
            const float4* rpb = rp + (size_t)kb * 32 * 16;
            const int jbb = jb0 + (kb * 32) * 16;
            #pragma unroll
            for (int k = 0; k < 32; ++k) {
                const float4 r = rpb[k * 16];            // ds_read offset:k*256
                const int j = jbb + k * 16;
                // ---- query A ----
                {
                    const float dot2 = (ax * r.x + ay * r.y) + az * r.z;
                    const float dd   = (acc_ + r.w) - dot2;      // == numpy d2
                    const bool l2 = dd < aD2;
                    const bool l1 = dd < aD1;
                    const bool l0 = dd < aD0;
                    aI2 = l2 ? (l1 ? aI1 : j) : aI2;
                    aI1 = l1 ? (l0 ? aI0 : j) : aI1;
                    aI0 = l0 ? j : aI0;
                    const float n2  = __builtin_amdgcn_fmed3f(dd, aD1, aD2);
                    const float n1  = __builtin_amdgcn_fmed3f(dd, aD0, aD1);
                    const float n0v = fminf(dd, aD0);
                    aD2 = n2; aD1 = n1; aD0 = n0v;
                }
                // ---- query B ----
                {
                    const float dot2 = (bx * r.x + by * r.y) + bz * r.z;
                    const float dd   = (bcc_ + r.w) - dot2;
                    const bool l2 = dd < bD2;
                    const bool l1 = dd < bD1;
                    const bool l0 = dd < bD0;
                    bI2 = l2 ? (l1 ? bI1 : j) : bI2;
                    bI1 = l1 ? (l0 ? bI0 : j) : bI1;
                    bI0 = l0 ? j : bI0;
                    const float n2  = __builtin_amdgcn_fmed3f(dd, bD1, bD2);
                    const float n1  = __builtin_amdgcn_fmed3f(dd, bD0, bD1);
                    const float n0v = fminf(dd, bD0);
                    bD2 = n2; bD1 = n1; bD0 = n0v;
                }
            }
        }
    }

    // lexicographic (d, idx) merge: lower index wins exact ties (stable top_k)
    // butterfly across the 16 sub-lanes (xor<16 stays in-group, in-wave)
    for (int off = 1; off < 16; off <<= 1) {
        {
            const float e0 = __shfl_xor(aD0, off, 64);
            const float e1 = __shfl_xor(aD1, off, 64);
            const float e2 = __shfl_xor(aD2, off, 64);
            const int   f0 = __shfl_xor(aI0, off, 64);
            const int   f1 = __shfl_xor(aI1, off, 64);
            const int   f2 = __shfl_xor(aI2, off, 64);
            auto ins = [&](float e, int f) {
                const bool l2 = (e < aD2) || (e == aD2 && f < aI2);
                const bool l1 = (e < aD1) || (e == aD1 && f < aI1);
                const bool l0 = (e < aD0) || (e == aD0 && f < aI0);
                aD2 = l2 ? (l1 ? aD1 : e) : aD2;  aI2 = l2 ? (l1 ? aI1 : f) : aI2;
                aD1 = l1 ? (l0 ? aD0 : e) : aD1;  aI1 = l1 ? (l0 ? aI0 : f) : aI1;
                aD0 = l0 ? e : aD0;               aI0 = l0 ? f : aI0;
            };
            ins(e0, f0); ins(e1, f1); ins(e2, f2);
        }
        {
            const float e0 = __shfl_xor(bD0, off, 64);
            const float e1 = __shfl_xor(bD1, off, 64);
            const float e2 = __shfl_xor(bD2, off, 64);
            const int   f0 = __shfl_xor(bI0, off, 64);
            const int   f1 = __shfl_xor(bI1, off, 64);
            const int   f2 = __shfl_xor(bI2, off, 64);
            auto ins = [&](float e, int f) {
                const bool l2 = (e < bD2) || (e == bD2 && f < bI2);
                const bool l1 = (e < bD1) || (e == bD1 && f < bI1);
                const bool l0 = (e < bD0) || (e == bD0 && f < bI0);
                bD2 = l2 ? (l1 ? bD1 : e) : bD2;  bI2 = l2 ? (l1 ? bI1 : f) : bI2;
                bD1 = l1 ? (l0 ? bD0 : e) : bD1;  bI1 = l1 ? (l0 ? bI0 : f) : bI1;
                bD0 = l0 ? e : bD0;               bI0 = l0 ? f : bI0;
            };
            ins(e0, f0); ins(e1, f1); ins(e2, f2);
        }
    }

    if (s == 0) {
        {
            float w0 = 1.0f / (aD0 + 1e-8f);     // IEEE divs, numpy order
            float w1 = 1.0f / (aD1 + 1e-8f);
            float w2 = 1.0f / (aD2 + 1e-8f);
            const float sum = (w0 + w1) + w2;
            wsI[(size_t)b * NN + nA] = make_int4(aI0, aI1, aI2, 0);
            wsW[(size_t)b * NN + nA] = make_float4(w0 / sum, w1 / sum, w2 / sum, 0.0f);
        }
        {
            float w0 = 1.0f / (bD0 + 1e-8f);
            float w1 = 1.0f / (bD1 + 1e-8f);
            float w2 = 1.0f / (bD2 + 1e-8f);
            const float sum = (w0 + w1) + w2;
            wsI[(size_t)b * NN + nA + 1] = make_int4(bI0, bI1, bI2, 0);
            wsW[(size_t)b * NN + nA + 1] = make_float4(w0 / sum, w1 / sum, w2 / sum, 0.0f);
        }
    }
}

// ===================== kernel 2: row-staged interpolation ====================
// Unchanged from round 3 (improved ~38 -> ~24 us there): 2 rows per block
// halves idx/w L2 re-reads; software-pipelined ws loads hide L2 latency.
#define TPB2 512
#define NIB  (BB * (CF + CT) / 2)   // 384 interp blocks (2 rows each)
#define NCB  32                     // copy blocks (4 pf rows each)

__global__ __launch_bounds__(TPB2, 8) void interp_kernel(
    const float* __restrict__ refF,        // [B,256,M]
    const float* __restrict__ refT,        // [B,128,M]
    const float* __restrict__ pf,          // [B,64,N]
    const int4*  __restrict__ wsI,         // [B,N]
    const float4* __restrict__ wsW,        // [B,N]
    float* __restrict__ out)               // [B,320,N] ++ [B,128,N]
{
#pragma clang fp contract(off)
    __shared__ float rowA[MM];             // 16 KB
    __shared__ float rowB[MM];             // 16 KB
    const int tid  = threadIdx.x;
    const int task = blockIdx.x;
    const size_t outT_base = (size_t)BB * (CF + CP) * NN;

    if (task >= NIB) {                     // -------- pf copy blocks --------
        const int t3 = task - NIB;         // 0..31, 4 rows each
        for (int j = 0; j < 4; ++j) {
            const int r  = t3 * 4 + j;
            const int bb = r >> 6;
            const int c  = r & (CP - 1);
            const float4* s4 = (const float4*)(pf + ((size_t)bb * CP + c) * NN);
            float4* d4 = (float4*)(out + ((size_t)bb * (CF + CP) + CF + c) * NN);
            for (int i = tid; i < NN / 4; i += TPB2) d4[i] = s4[i];
        }
        return;                            // block-uniform exit
    }

    const int r0 = task * 2;               // rows r0, r0+1 (same b, same class)
    const float* src0;
    float* dst0;
    int b;
    if (r0 < BB * CF) {                    // interpolated features
        b = r0 >> 8;
        const int c = r0 & (CF - 1);
        src0 = refF + ((size_t)b * CF + c) * MM;
        dst0 = out + ((size_t)b * (CF + CP) + c) * NN;
    } else {                               // interpolated t_embed
        const int r2 = r0 - BB * CF;
        b = r2 >> 7;
        const int c = r2 & (CT - 1);
        src0 = refT + ((size_t)b * CT + c) * MM;
        dst0 = out + outT_base + ((size_t)b * CT + c) * NN;
    }
    const float* src1 = src0 + MM;
    float* dst1 = dst0 + NN;

    for (int i = tid; i < MM / 4; i += TPB2) {
        ((float4*)rowA)[i] = ((const float4*)src0)[i];
        ((float4*)rowB)[i] = ((const float4*)src1)[i];
    }
    __syncthreads();

    const int4*   wi = wsI + (size_t)b * NN;
    const float4* ww = wsW + (size_t)b * NN;

    auto clampi = [](int v) { return v < 0 ? 0 : (v > MM - 1 ? MM - 1 : v); };

    int4   id = wi[tid];
    float4 w  = ww[tid];
    for (int nq = tid; nq < NN; nq += TPB2) {
        const int nq2 = nq + TPB2;
        int4   idn;
        float4 wn;
        if (nq2 < NN) { idn = wi[nq2]; wn = ww[nq2]; }   // prefetch next
        const int a0 = clampi(id.x), a1 = clampi(id.y), a2 = clampi(id.z);
        dst0[nq] = (w.x * rowA[a0] + w.y * rowA[a1]) + w.z * rowA[a2];
        dst1[nq] = (w.x * rowB[a0] + w.y * rowB[a1]) + w.z * rowB[a2];
        id = idn; w = wn;
    }
}

extern "C" void kernel_launch(void* const* d_in, const int* in_sizes, int n_in,
                              void* d_out, int out_size, void* d_ws, size_t ws_size,
                              hipStream_t stream) {
    const float* coords     = (const float*)d_in[0];
    const float* ref_coords = (const float*)d_in[1];
    const float* refF       = (const float*)d_in[2];
    const float* refT       = (const float*)d_in[3];
    const float* pf         = (const float*)d_in[4];
    float* out = (float*)d_out;

    int4*   wsI = (int4*)d_ws;
    float4* wsW = (float4*)((char*)d_ws + (size_t)BB * NN * sizeof(int4));

    hipLaunchKernelGGL(knn_kernel, dim3(NN / NPB1, BB), dim3(TPB1), 0, stream,
                       coords, ref_coords, wsI, wsW);
    hipLaunchKernelGGL(interp_kernel, dim3(NIB + NCB), dim3(TPB2), 0, stream,
                       refF, refT, pf, wsI, wsW, out);
}

// Round 5
// 180.357 us; speedup vs baseline: 1.0143x; 1.0143x over previous
//
#include <hip/hip_runtime.h>
#include <cstdint>

#define BB 2
#define NN 16384
#define MM 4096
#define CF 256
#define CT 128
#define CP 64

// ======================= kernel 1: 3-NN -> workspace =======================
// Round-5: R2's proven-best instruction stream + gate geometry, with ONE
// change: split-K over the ref range. Each block = 32 queries x 512 threads;
// half 0 (threads 0..255) scans elems [0,1024) of each staged chunk, half 1
// scans [1024,2048). Per-wave geometry identical to R2 (8 queries x 8
// sub-lanes, __any covers 64 pairs). Grid doubles to 1024 -> 8 waves/SIMD
// resident (R2 was stall-bound at 4). Cross-half merge via LDS uses the
// lexicographic ins() -- order-independent over (d,j), so the partition
// cannot change the selected triple (top_k lowest-index tie rule kept).
// Bit-exactness: dd formula (pre-doubled refs, numpy sum order, contract
// off), strict-< scan network, min/med3 value network -- all unchanged.
#define TPB1 512
#define NPB1 32
#define CHUNK 2048
#define HALFE 1024

__global__ __launch_bounds__(TPB1, 8) void knn_kernel(
    const float* __restrict__ coords,      // [B,N,3]
    const float* __restrict__ ref_coords,  // [B,M,3]
    int4* __restrict__ wsI,                // [B,N] {i0,i1,i2,-}
    float4* __restrict__ wsW)              // [B,N] {w0,w1,w2,-}
{
#pragma clang fp contract(off)
    __shared__ float4 refs[CHUNK];          // 32 KB (2x, 2y, 2z, rr)
    __shared__ float  mD[NPB1][2][4];       // 1 KB cross-half merge buffers
    __shared__ int    mI[NPB1][2][4];       // 1 KB

    const int tid = threadIdx.x;
    const int b   = blockIdx.y;
    const int n0  = blockIdx.x * NPB1;

    const int pl = (tid >> 3) & (NPB1 - 1); // query-in-block 0..31
    const int s  = tid & 7;                 // sub-lane 0..7
    const int h  = tid >> 8;                // ref half 0/1
    const int n  = n0 + pl;

    const float* cp = coords + ((size_t)b * NN + n) * 3;
    const float cx = cp[0];
    const float cy = cp[1];
    const float cz = cp[2];
    const float cc = (cx * cx + cy * cy) + cz * cz;   // numpy sum order

    float d0 = INFINITY, d1 = INFINITY, d2v = INFINITY;
    int   i0 = 0, i1 = 0, i2 = 0;
    float tau = INFINITY;               // group pruning threshold
    float thr = INFINITY;               // min(d2v, tau)

    const float* rc = ref_coords + (size_t)b * MM * 3;

    for (int ch = 0; ch < MM / CHUNK; ++ch) {
        __syncthreads();                 // refs[] reuse guard
        for (int e = tid; e < CHUNK; e += TPB1) {
            const int j = ch * CHUNK + e;
            const float x = rc[3 * j + 0];
            const float y = rc[3 * j + 1];
            const float z = rc[3 * j + 2];
            // rr from ORIGINAL coords (numpy order); xyz pre-doubled (exact:
            // fl(c*(2r)) = 2*fl(c*r), fl(2a+2b) = 2*fl(a+b) at these scales)
            refs[e] = make_float4(x + x, y + y, z + z, (x * x + y * y) + z * z);
        }
        __syncthreads();

        const int ebase = h * HALFE + s;    // this half's lane base in chunk
        const int jbase = ch * CHUNK + ebase;
        // lane scans e = ebase + 8k ascending -> strict '<' keeps lowest idx;
        // tau refresh every 32 iterations (R2 cadence)
        for (int it0 = 0; it0 < HALFE / 8; it0 += 32) {
            #pragma unroll 4
            for (int k = 0; k < 32; ++k) {
                const int off8 = (it0 + k) << 3;
                const float4 r = refs[ebase + off8];
                // dot2 == 2*((cx*rx + cy*ry) + cz*rz) bit-exactly
                const float dot2 = (cx * r.x + cy * r.y) + cz * r.z;
                const float dd   = (cc + r.w) - dot2;        // == numpy d2
                if (__any(dd < thr)) {
                    const int j = jbase + off8;
                    const bool l2 = dd < d2v;
                    const bool l1 = dd < d1;
                    const bool l0 = dd < d0;
                    i2 = l2 ? (l1 ? i1 : j) : i2;
                    i1 = l1 ? (l0 ? i0 : j) : i1;
                    i0 = l0 ? j : i0;
                    const float n2  = __builtin_amdgcn_fmed3f(dd, d1, d2v);
                    const float n1  = __builtin_amdgcn_fmed3f(dd, d0, d1);
                    const float n0v = fminf(dd, d0);
                    d2v = n2; d1 = n1; d0 = n0v;
                    thr = fminf(d2v, tau);
                }
            }
            // refresh tau = min of this query's 8 sub-lanes' d2v (in-wave)
            float tt = d2v;
            tt = fminf(tt, __shfl_xor(tt, 1, 64));
            tt = fminf(tt, __shfl_xor(tt, 2, 64));
            tt = fminf(tt, __shfl_xor(tt, 4, 64));
            tau = tt;
            thr = fminf(d2v, tau);
        }
    }

    // lexicographic (d, idx) insert: lower index wins exact ties (stable
    // top_k); order-independent -> safe for butterfly AND cross-half merge
    auto ins = [&](float e, int f) {
        const bool l2 = (e < d2v) || (e == d2v && f < i2);
        const bool l1 = (e < d1)  || (e == d1  && f < i1);
        const bool l0 = (e < d0)  || (e == d0  && f < i0);
        d2v = l2 ? (l1 ? d1 : e) : d2v;  i2 = l2 ? (l1 ? i1 : f) : i2;
        d1  = l1 ? (l0 ? d0 : e) : d1;   i1 = l1 ? (l0 ? i0 : f) : i1;
        d0  = l0 ? e : d0;               i0 = l0 ? f : i0;
    };

    // butterfly across the 8 sub-lanes (xor<8 stays in-group, in-wave)
    for (int off = 1; off < 8; off <<= 1) {
        const float e0 = __shfl_xor(d0,  off, 64);
        const float e1 = __shfl_xor(d1,  off, 64);
        const float e2 = __shfl_xor(d2v, off, 64);
        const int   f0 = __shfl_xor(i0,  off, 64);
        const int   f1 = __shfl_xor(i1,  off, 64);
        const int   f2 = __shfl_xor(i2,  off, 64);
        ins(e0, f0);
        ins(e1, f1);
        ins(e2, f2);
    }

    if (s == 0) {
        mD[pl][h][0] = d0;  mD[pl][h][1] = d1;  mD[pl][h][2] = d2v;
        mI[pl][h][0] = i0;  mI[pl][h][1] = i1;  mI[pl][h][2] = i2;
    }
    __syncthreads();

    if (h == 0 && s == 0) {             // one lane per query merges halves
        ins(mD[pl][1][0], mI[pl][1][0]);
        ins(mD[pl][1][1], mI[pl][1][1]);
        ins(mD[pl][1][2], mI[pl][1][2]);
        float w0 = 1.0f / (d0  + 1e-8f);     // IEEE divs, numpy order
        float w1 = 1.0f / (d1  + 1e-8f);
        float w2 = 1.0f / (d2v + 1e-8f);
        const float sum = (w0 + w1) + w2;
        wsI[(size_t)b * NN + n] = make_int4(i0, i1, i2, 0);
        wsW[(size_t)b * NN + n] = make_float4(w0 / sum, w1 / sum, w2 / sum, 0.0f);
    }
}

// ===================== kernel 2: row-staged interpolation ====================
// Unchanged from round 3 (improved ~38 -> ~24 us there): 2 rows per block
// halves idx/w L2 re-reads; software-pipelined ws loads hide L2 latency.
#define TPB2 512
#define NIB  (BB * (CF + CT) / 2)   // 384 interp blocks (2 rows each)
#define NCB  32                     // copy blocks (4 pf rows each)

__global__ __launch_bounds__(TPB2, 8) void interp_kernel(
    const float* __restrict__ refF,        // [B,256,M]
    const float* __restrict__ refT,        // [B,128,M]
    const float* __restrict__ pf,          // [B,64,N]
    const int4*  __restrict__ wsI,         // [B,N]
    const float4* __restrict__ wsW,        // [B,N]
    float* __restrict__ out)               // [B,320,N] ++ [B,128,N]
{
#pragma clang fp contract(off)
    __shared__ float rowA[MM];             // 16 KB
    __shared__ float rowB[MM];             // 16 KB
    const int tid  = threadIdx.x;
    const int task = blockIdx.x;
    const size_t outT_base = (size_t)BB * (CF + CP) * NN;

    if (task >= NIB) {                     // -------- pf copy blocks --------
        const int t3 = task - NIB;         // 0..31, 4 rows each
        for (int j = 0; j < 4; ++j) {
            const int r  = t3 * 4 + j;
            const int bb = r >> 6;
            const int c  = r & (CP - 1);
            const float4* s4 = (const float4*)(pf + ((size_t)bb * CP + c) * NN);
            float4* d4 = (float4*)(out + ((size_t)bb * (CF + CP) + CF + c) * NN);
            for (int i = tid; i < NN / 4; i += TPB2) d4[i] = s4[i];
        }
        return;                            // block-uniform exit
    }

    const int r0 = task * 2;               // rows r0, r0+1 (same b, same class)
    const float* src0;
    float* dst0;
    int b;
    if (r0 < BB * CF) {                    // interpolated features
        b = r0 >> 8;
        const int c = r0 & (CF - 1);
        src0 = refF + ((size_t)b * CF + c) * MM;
        dst0 = out + ((size_t)b * (CF + CP) + c) * NN;
    } else {                               // interpolated t_embed
        const int r2 = r0 - BB * CF;
        b = r2 >> 7;
        const int c = r2 & (CT - 1);
        src0 = refT + ((size_t)b * CT + c) * MM;
        dst0 = out + outT_base + ((size_t)b * CT + c) * NN;
    }
    const float* src1 = src0 + MM;
    float* dst1 = dst0 + NN;

    for (int i = tid; i < MM / 4; i += TPB2) {
        ((float4*)rowA)[i] = ((const float4*)src0)[i];
        ((float4*)rowB)[i] = ((const float4*)src1)[i];
    }
    __syncthreads();

    const int4*   wi = wsI + (size_t)b * NN;
    const float4* ww = wsW + (size_t)b * NN;

    auto clampi = [](int v) { return v < 0 ? 0 : (v > MM - 1 ? MM - 1 : v); };

    int4   id = wi[tid];
    float4 w  = ww[tid];
    for (int nq = tid; nq < NN; nq += TPB2) {
        const int nq2 = nq + TPB2;
        int4   idn;
        float4 wn;
        if (nq2 < NN) { idn = wi[nq2]; wn = ww[nq2]; }   // prefetch next
        const int a0 = clampi(id.x), a1 = clampi(id.y), a2 = clampi(id.z);
        dst0[nq] = (w.x * rowA[a0] + w.y * rowA[a1]) + w.z * rowA[a2];
        dst1[nq] = (w.x * rowB[a0] + w.y * rowB[a1]) + w.z * rowB[a2];
        id = idn; w = wn;
    }
}

extern "C" void kernel_launch(void* const* d_in, const int* in_sizes, int n_in,
                              void* d_out, int out_size, void* d_ws, size_t ws_size,
                              hipStream_t stream) {
    const float* coords     = (const float*)d_in[0];
    const float* ref_coords = (const float*)d_in[1];
    const float* refF       = (const float*)d_in[2];
    const float* refT       = (const float*)d_in[3];
    const float* pf         = (const float*)d_in[4];
    float* out = (float*)d_out;

    int4*   wsI = (int4*)d_ws;
    float4* wsW = (float4*)((char*)d_ws + (size_t)BB * NN * sizeof(int4));

    hipLaunchKernelGGL(knn_kernel, dim3(NN / NPB1, BB), dim3(TPB1), 0, stream,
                       coords, ref_coords, wsI, wsW);
    hipLaunchKernelGGL(interp_kernel, dim3(NIB + NCB), dim3(TPB2), 0, stream,
                       refF, refT, pf, wsI, wsW, out);
}